// Round 1
// baseline (403.382 us; speedup 1.0000x reference)
//
#include <hip/hip_runtime.h>

typedef __attribute__((ext_vector_type(4))) float f32x4;
typedef __attribute__((ext_vector_type(8))) short bf16x8;

__device__ __forceinline__ unsigned short f2bf(float f) {
  unsigned u = __float_as_uint(f);
  u += 0x7fff + ((u >> 16) & 1);   // round-to-nearest-even
  return (unsigned short)(u >> 16);
}
__device__ __forceinline__ float bf2f(unsigned short h) {
  return __uint_as_float(((unsigned)h) << 16);
}

__device__ __forceinline__ void gload_lds16(const void* g, void* lds) {
  __builtin_amdgcn_global_load_lds(
      (const __attribute__((address_space(1))) unsigned int*)g,
      (__attribute__((address_space(3))) unsigned int*)lds, 16, 0, 0);
}

// ---------------------------------------------------------------- cast f32->bf16
__global__ void cast_f32_bf16(const float* __restrict__ in,
                              unsigned short* __restrict__ out, int n4) {
  int i = blockIdx.x * blockDim.x + threadIdx.x;
  if (i >= n4) return;
  float4 v = ((const float4*)in)[i];
  ushort4 o;
  o.x = f2bf(v.x); o.y = f2bf(v.y); o.z = f2bf(v.z); o.w = f2bf(v.w);
  ((ushort4*)out)[i] = o;
}

// ---------------------------------------------------------------- RoPE cos/sin table
__global__ void rope_table(float2* __restrict__ cs) {
  int idx = blockIdx.x * blockDim.x + threadIdx.x;  // 2048*32
  if (idx >= 2048 * 32) return;
  int t = idx >> 5, i = idx & 31;
  float inv = powf(10000.0f, -(float)(2 * i) / 64.0f);
  float a = (float)t * inv;
  cs[idx] = make_float2(cosf(a), sinf(a));
}

// ---------------------------------------------------------------- RoPE apply (q,k in-place)
__global__ void rope_apply(unsigned short* __restrict__ qkv,
                           const float2* __restrict__ cs) {
  int idx = blockIdx.x * blockDim.x + threadIdx.x;  // B*T*H*32 = 4194304
  int i = idx & 31;
  int h = (idx >> 5) & 15;
  int t = (idx >> 9) & 2047;
  int b = idx >> 20;
  float2 v = cs[(t << 5) | i];
  size_t base = ((size_t)((b << 11) + t)) * 3072 + h * 64 + 2 * i;
#pragma unroll
  for (int part = 0; part < 2; ++part) {           // q then k
    unsigned short* p = qkv + base + part * 1024;
    unsigned pr = *(unsigned*)p;
    float e = bf2f((unsigned short)(pr & 0xffff));
    float o = bf2f((unsigned short)(pr >> 16));
    float ne = e * v.x - o * v.y;
    float no = e * v.y + o * v.x;
    *(unsigned*)p = (unsigned)f2bf(ne) | ((unsigned)f2bf(no) << 16);
  }
}

// ---------------------------------------------------------------- GEMM: C = A(MxK) * B(NxK)^T + bias
template <int OUT_BF16>
__global__ __launch_bounds__(256, 2) void gemm_bt(
    const unsigned short* __restrict__ A, const unsigned short* __restrict__ B,
    const float* __restrict__ bias, void* __restrict__ Cout,
    int M, int N, int K) {
  __shared__ unsigned short lA[128 * 64];
  __shared__ unsigned short lB[128 * 64];
  const int tiles_n = N >> 7;
  const int bm = blockIdx.x / tiles_n;
  const int bn = blockIdx.x % tiles_n;
  const int tid = threadIdx.x;
  const int w = tid >> 6, l = tid & 63;
  const int l15 = l & 15, lq = l >> 4;
  const int wm = (w >> 1) * 64, wn = (w & 1) * 64;
  const int m0 = bm << 7, n0 = bn << 7;
  const int arow = l >> 3;         // row within 8-row group
  const int acol = (l & 7) * 8;    // element col (8 bf16 = 16B)
  f32x4 acc[4][4] = {};

  for (int k0 = 0; k0 < K; k0 += 64) {
    __syncthreads();
#pragma unroll
    for (int it = 0; it < 4; ++it) {
      const int rb = it * 32 + w * 8;
      gload_lds16(A + (size_t)(m0 + rb + arow) * K + k0 + acol, &lA[rb * 64]);
      gload_lds16(B + (size_t)(n0 + rb + arow) * K + k0 + acol, &lB[rb * 64]);
    }
    __syncthreads();
#pragma unroll
    for (int ks = 0; ks < 2; ++ks) {
      bf16x8 af[4], bfr[4];
#pragma unroll
      for (int mi = 0; mi < 4; ++mi)
        af[mi] = *(const bf16x8*)&lA[(wm + mi * 16 + l15) * 64 + ks * 32 + lq * 8];
#pragma unroll
      for (int ni = 0; ni < 4; ++ni)
        bfr[ni] = *(const bf16x8*)&lB[(wn + ni * 16 + l15) * 64 + ks * 32 + lq * 8];
#pragma unroll
      for (int mi = 0; mi < 4; ++mi)
#pragma unroll
        for (int ni = 0; ni < 4; ++ni)
          acc[mi][ni] = __builtin_amdgcn_mfma_f32_16x16x32_bf16(
              af[mi], bfr[ni], acc[mi][ni], 0, 0, 0);
    }
  }

#pragma unroll
  for (int ni = 0; ni < 4; ++ni) {
    const int c = n0 + wn + ni * 16 + l15;
    const float bv = bias[c];
#pragma unroll
    for (int mi = 0; mi < 4; ++mi) {
#pragma unroll
      for (int j = 0; j < 4; ++j) {
        const int r = m0 + wm + mi * 16 + lq * 4 + j;
        const float v = acc[mi][ni][j] + bv;
        if (OUT_BF16)
          ((unsigned short*)Cout)[(size_t)r * N + c] = f2bf(v);
        else
          ((float*)Cout)[(size_t)r * N + c] = v;
      }
    }
  }
}

// ---------------------------------------------------------------- flash attention fwd
// qkv: [B*T][3072] bf16 (q|k|v each [H=16][hd=64]); aout: [B*T][1024] bf16
__global__ __launch_bounds__(256) void attn_fwd(
    const unsigned short* __restrict__ qkv, unsigned short* __restrict__ aout) {
  __shared__ unsigned short lK[64 * 64];        // linear (global_load_lds dest)
  __shared__ unsigned short lVt[64 * 72];       // V transposed, padded stride
  __shared__ unsigned short lP[4 * 16 * 72];    // per-wave P tile

  // XCD-aware decode: all 32 q-tiles of one (b,h) land on the same XCD
  const int g = blockIdx.x;              // 2048 blocks
  const int xcd = g & 7;
  const int j2 = g >> 3;
  const int bh = ((j2 >> 5) << 3) + xcd; // 0..63
  const int qt = j2 & 31;
  const int h = bh & 15, b = bh >> 4;

  const int tid = threadIdx.x;
  const int w = tid >> 6, l = tid & 63;
  const int l15 = l & 15, lq = l >> 4;

  const size_t bt_base = (size_t)(b * 2048) * 3072;

  // Q fragments in registers (A-operand: row = lane&15, k = (lane>>4)*8+i)
  const unsigned short* Qp =
      qkv + bt_base + (size_t)(qt * 64 + w * 16 + l15) * 3072 + h * 64;
  bf16x8 qf[2];
  qf[0] = *(const bf16x8*)(Qp + lq * 8);
  qf[1] = *(const bf16x8*)(Qp + 32 + lq * 8);

  const unsigned short* Kp = qkv + bt_base + 1024 + h * 64;
  const unsigned short* Vp = qkv + bt_base + 2048 + h * 64;

  f32x4 o_acc[4] = {};
  float m_j[4], l_j[4];
#pragma unroll
  for (int j = 0; j < 4; ++j) { m_j[j] = -1e30f; l_j[j] = 0.f; }

  const int vr = tid >> 2;            // V stage: row 0..63
  const int vc0 = (tid & 3) * 16;     // 16 cols per thread

  for (int kt = 0; kt < 32; ++kt) {
    __syncthreads();
    // stage K via global_load_lds (2 issues x 4KB)
#pragma unroll
    for (int it = 0; it < 2; ++it) {
      const int rb = it * 32 + w * 8;
      gload_lds16(Kp + (size_t)(kt * 64 + rb + (l >> 3)) * 3072 + (l & 7) * 8,
                  &lK[rb * 64]);
    }
    // stage V transposed through registers
    {
      const unsigned short* vp = Vp + (size_t)(kt * 64 + vr) * 3072 + vc0;
      bf16x8 v0 = *(const bf16x8*)vp;
      bf16x8 v1 = *(const bf16x8*)(vp + 8);
#pragma unroll
      for (int i2 = 0; i2 < 8; ++i2) {
        lVt[(vc0 + i2) * 72 + vr] = (unsigned short)v0[i2];
        lVt[(vc0 + 8 + i2) * 72 + vr] = (unsigned short)v1[i2];
      }
    }
    __syncthreads();

    // S = Q K^T  (rows q, cols k)
    f32x4 s[4] = {};
#pragma unroll
    for (int ks = 0; ks < 2; ++ks) {
#pragma unroll
      for (int ni = 0; ni < 4; ++ni) {
        bf16x8 kf = *(const bf16x8*)&lK[(ni * 16 + l15) * 64 + ks * 32 + lq * 8];
        s[ni] = __builtin_amdgcn_mfma_f32_16x16x32_bf16(qf[ks], kf, s[ni], 0, 0, 0);
      }
    }
#pragma unroll
    for (int ni = 0; ni < 4; ++ni) s[ni] *= 0.125f;   // 1/sqrt(64)

    // online softmax; row q = (lane>>4)*4 + j, its 64 cols live in the 16
    // lanes sharing lane>>4 (4 frags x lane&15) -> shfl_xor 1,2,4,8 reduce
    float mx[4], rs[4], alpha[4];
#pragma unroll
    for (int j = 0; j < 4; ++j) {
      float m = -1e30f;
#pragma unroll
      for (int ni = 0; ni < 4; ++ni) m = fmaxf(m, s[ni][j]);
      mx[j] = m;
    }
#pragma unroll
    for (int j = 0; j < 4; ++j) {
#pragma unroll
      for (int off = 1; off < 16; off <<= 1)
        mx[j] = fmaxf(mx[j], __shfl_xor(mx[j], off));
      const float mn = fmaxf(m_j[j], mx[j]);
      alpha[j] = __expf(m_j[j] - mn);
      m_j[j] = mn;
      rs[j] = 0.f;
    }
#pragma unroll
    for (int ni = 0; ni < 4; ++ni) {
#pragma unroll
      for (int j = 0; j < 4; ++j) {
        const float p = __expf(s[ni][j] - m_j[j]);
        s[ni][j] = p;
        rs[j] += p;
      }
    }
#pragma unroll
    for (int j = 0; j < 4; ++j) {
#pragma unroll
      for (int off = 1; off < 16; off <<= 1)
        rs[j] += __shfl_xor(rs[j], off);
      l_j[j] = l_j[j] * alpha[j] + rs[j];
    }
#pragma unroll
    for (int df = 0; df < 4; ++df) {
      f32x4 t = o_acc[df];
      t[0] *= alpha[0]; t[1] *= alpha[1]; t[2] *= alpha[2]; t[3] *= alpha[3];
      o_acc[df] = t;
    }

    // P -> LDS (re-layout to A-operand), per-wave region, no barrier needed
#pragma unroll
    for (int ni = 0; ni < 4; ++ni)
#pragma unroll
      for (int j = 0; j < 4; ++j)
        lP[w * 1152 + (lq * 4 + j) * 72 + ni * 16 + l15] = f2bf(s[ni][j]);

    // O += P V   (B-operand: col=d from lVt rows, inner k)
#pragma unroll
    for (int ks = 0; ks < 2; ++ks) {
      bf16x8 pf = *(const bf16x8*)&lP[w * 1152 + l15 * 72 + ks * 32 + lq * 8];
#pragma unroll
      for (int df = 0; df < 4; ++df) {
        bf16x8 vf = *(const bf16x8*)&lVt[(df * 16 + l15) * 72 + ks * 32 + lq * 8];
        o_acc[df] = __builtin_amdgcn_mfma_f32_16x16x32_bf16(pf, vf, o_acc[df], 0, 0, 0);
      }
    }
  }

  float inv[4];
#pragma unroll
  for (int j = 0; j < 4; ++j) inv[j] = 1.0f / l_j[j];
  unsigned short* op = aout +
      (size_t)(b * 2048 + qt * 64 + w * 16 + lq * 4) * 1024 + h * 64 + l15;
#pragma unroll
  for (int j = 0; j < 4; ++j)
#pragma unroll
    for (int df = 0; df < 4; ++df)
      op[(size_t)j * 1024 + df * 16] = f2bf(o_acc[df][j] * inv[j]);
}

// ---------------------------------------------------------------- launch
extern "C" void kernel_launch(void* const* d_in, const int* in_sizes, int n_in,
                              void* d_out, int out_size, void* d_ws, size_t ws_size,
                              hipStream_t stream) {
  const float* x     = (const float*)d_in[0];
  const float* w_qkv = (const float*)d_in[1];
  const float* b_qkv = (const float*)d_in[2];
  const float* w_out = (const float*)d_in[3];
  const float* b_out = (const float*)d_in[4];
  float* out = (float*)d_out;

  char* ws = (char*)d_ws;
  unsigned short* x_bf    = (unsigned short*)(ws);             // 16 MB
  unsigned short* wqkv_bf = (unsigned short*)(ws + 16777216);  // 6 MB
  unsigned short* wout_bf = (unsigned short*)(ws + 23068672);  // 2 MB
  unsigned short* qkv     = (unsigned short*)(ws + 25165824);  // 48 MB
  unsigned short* aout    = (unsigned short*)(ws + 75497472);  // 16 MB
  float2* cs              = (float2*)(ws + 92274688);          // 512 KB

  cast_f32_bf16<<<2097152 / 256, 256, 0, stream>>>(x, x_bf, 2097152);
  cast_f32_bf16<<<786432 / 256, 256, 0, stream>>>(w_qkv, wqkv_bf, 786432);
  cast_f32_bf16<<<262144 / 256, 256, 0, stream>>>(w_out, wout_bf, 262144);
  rope_table<<<65536 / 256, 256, 0, stream>>>(cs);

  // qkv = x @ w_qkv^T + b_qkv   (M=8192, N=3072, K=1024), bf16 out
  gemm_bt<1><<<64 * 24, 256, 0, stream>>>(x_bf, wqkv_bf, b_qkv, qkv,
                                          8192, 3072, 1024);
  rope_apply<<<4194304 / 256, 256, 0, stream>>>(qkv, cs);
  attn_fwd<<<2048, 256, 0, stream>>>(qkv, aout);
  // out = attn @ w_out^T + b_out (M=8192, N=1024, K=1024), f32 out
  gemm_bt<0><<<64 * 8, 256, 0, stream>>>(aout, wout_bf, b_out, out,
                                         8192, 1024, 1024);
}

// Round 2
// 378.106 us; speedup vs baseline: 1.0668x; 1.0668x over previous
//
#include <hip/hip_runtime.h>

typedef __attribute__((ext_vector_type(4))) float f32x4;
typedef __attribute__((ext_vector_type(8))) short bf16x8;

__device__ __forceinline__ unsigned short f2bf(float f) {
  unsigned u = __float_as_uint(f);
  u += 0x7fff + ((u >> 16) & 1);   // round-to-nearest-even
  return (unsigned short)(u >> 16);
}
__device__ __forceinline__ float bf2f(unsigned short h) {
  return __uint_as_float(((unsigned)h) << 16);
}

__device__ __forceinline__ void gload_lds16(const void* g, void* lds) {
  __builtin_amdgcn_global_load_lds(
      (const __attribute__((address_space(1))) unsigned int*)g,
      (__attribute__((address_space(3))) unsigned int*)lds, 16, 0, 0);
}

// ---------------------------------------------------------------- cast f32->bf16
__global__ void cast_f32_bf16(const float* __restrict__ in,
                              unsigned short* __restrict__ out, int n4) {
  int i = blockIdx.x * blockDim.x + threadIdx.x;
  if (i >= n4) return;
  float4 v = ((const float4*)in)[i];
  ushort4 o;
  o.x = f2bf(v.x); o.y = f2bf(v.y); o.z = f2bf(v.z); o.w = f2bf(v.w);
  ((ushort4*)out)[i] = o;
}

// ---------------------------------------------------------------- RoPE cos/sin table
__global__ void rope_table(float2* __restrict__ cs) {
  int idx = blockIdx.x * blockDim.x + threadIdx.x;  // 2048*32
  if (idx >= 2048 * 32) return;
  int t = idx >> 5, i = idx & 31;
  float inv = powf(10000.0f, -(float)(2 * i) / 64.0f);
  float a = (float)t * inv;
  cs[idx] = make_float2(cosf(a), sinf(a));
}

// ---------------------------------------------------------------- RoPE apply (q,k in-place)
__global__ void rope_apply(unsigned short* __restrict__ qkv,
                           const float2* __restrict__ cs) {
  int idx = blockIdx.x * blockDim.x + threadIdx.x;  // B*T*H*32 = 4194304
  int i = idx & 31;
  int h = (idx >> 5) & 15;
  int t = (idx >> 9) & 2047;
  int b = idx >> 20;
  float2 v = cs[(t << 5) | i];
  size_t base = ((size_t)((b << 11) + t)) * 3072 + h * 64 + 2 * i;
#pragma unroll
  for (int part = 0; part < 2; ++part) {           // q then k
    unsigned short* p = qkv + base + part * 1024;
    unsigned pr = *(unsigned*)p;
    float e = bf2f((unsigned short)(pr & 0xffff));
    float o = bf2f((unsigned short)(pr >> 16));
    float ne = e * v.x - o * v.y;
    float no = e * v.y + o * v.x;
    *(unsigned*)p = (unsigned)f2bf(ne) | ((unsigned)f2bf(no) << 16);
  }
}

// ---------------------------------------------------------------- GEMM: C = A(MxK) * B(NxK)^T + bias
template <int OUT_BF16>
__global__ __launch_bounds__(256, 2) void gemm_bt(
    const unsigned short* __restrict__ A, const unsigned short* __restrict__ B,
    const float* __restrict__ bias, void* __restrict__ Cout,
    int M, int N, int K) {
  __shared__ unsigned short lA[128 * 64];
  __shared__ unsigned short lB[128 * 64];
  const int tiles_n = N >> 7;
  const int bm = blockIdx.x / tiles_n;
  const int bn = blockIdx.x % tiles_n;
  const int tid = threadIdx.x;
  const int w = tid >> 6, l = tid & 63;
  const int l15 = l & 15, lq = l >> 4;
  const int wm = (w >> 1) * 64, wn = (w & 1) * 64;
  const int m0 = bm << 7, n0 = bn << 7;
  const int arow = l >> 3;         // row within 8-row group
  const int acol = (l & 7) * 8;    // element col (8 bf16 = 16B)
  f32x4 acc[4][4] = {};

  for (int k0 = 0; k0 < K; k0 += 64) {
    __syncthreads();
#pragma unroll
    for (int it = 0; it < 4; ++it) {
      const int rb = it * 32 + w * 8;
      gload_lds16(A + (size_t)(m0 + rb + arow) * K + k0 + acol, &lA[rb * 64]);
      gload_lds16(B + (size_t)(n0 + rb + arow) * K + k0 + acol, &lB[rb * 64]);
    }
    __syncthreads();
#pragma unroll
    for (int ks = 0; ks < 2; ++ks) {
      bf16x8 af[4], bfr[4];
#pragma unroll
      for (int mi = 0; mi < 4; ++mi)
        af[mi] = *(const bf16x8*)&lA[(wm + mi * 16 + l15) * 64 + ks * 32 + lq * 8];
#pragma unroll
      for (int ni = 0; ni < 4; ++ni)
        bfr[ni] = *(const bf16x8*)&lB[(wn + ni * 16 + l15) * 64 + ks * 32 + lq * 8];
#pragma unroll
      for (int mi = 0; mi < 4; ++mi)
#pragma unroll
        for (int ni = 0; ni < 4; ++ni)
          acc[mi][ni] = __builtin_amdgcn_mfma_f32_16x16x32_bf16(
              af[mi], bfr[ni], acc[mi][ni], 0, 0, 0);
    }
  }

#pragma unroll
  for (int ni = 0; ni < 4; ++ni) {
    const int c = n0 + wn + ni * 16 + l15;
    const float bv = bias[c];
#pragma unroll
    for (int mi = 0; mi < 4; ++mi) {
#pragma unroll
      for (int j = 0; j < 4; ++j) {
        const int r = m0 + wm + mi * 16 + lq * 4 + j;
        const float v = acc[mi][ni][j] + bv;
        if (OUT_BF16)
          ((unsigned short*)Cout)[(size_t)r * N + c] = f2bf(v);
        else
          ((float*)Cout)[(size_t)r * N + c] = v;
      }
    }
  }
}

// ---------------------------------------------------------------- flash attention fwd
// qkv: [B*T][3072] bf16 (q|k|v each [H=16][hd=64]); aout: [B*T][1024] bf16
// v2: K XOR-swizzled (pre-swizzled gload_lds source + swizzled ds_read),
//     double-buffered K/Vt, single barrier per KV tile, deferred V write.
__global__ __launch_bounds__(256, 3) void attn_fwd(
    const unsigned short* __restrict__ qkv, unsigned short* __restrict__ aout) {
  __shared__ unsigned short lK[2 * 64 * 64];    // swizzled chunks, gload_lds dest
  __shared__ unsigned short lVt[2 * 64 * 72];   // V transposed, padded stride
  __shared__ unsigned short lP[4 * 16 * 72];    // per-wave P tile

  // XCD-aware decode: all 32 q-tiles of one (b,h) land on the same XCD
  const int g = blockIdx.x;              // 2048 blocks
  const int xcd = g & 7;
  const int j2 = g >> 3;
  const int bh = ((j2 >> 5) << 3) + xcd; // 0..63
  const int qt = j2 & 31;
  const int h = bh & 15, b = bh >> 4;

  const int tid = threadIdx.x;
  const int w = tid >> 6, l = tid & 63;
  const int l15 = l & 15, lq = l >> 4;

  const size_t bt_base = (size_t)(b * 2048) * 3072;

  // Q fragments in registers (A-operand: row = lane&15, k = (lane>>4)*8+i)
  const unsigned short* Qp =
      qkv + bt_base + (size_t)(qt * 64 + w * 16 + l15) * 3072 + h * 64;
  bf16x8 qf[2];
  qf[0] = *(const bf16x8*)(Qp + lq * 8);
  qf[1] = *(const bf16x8*)(Qp + 32 + lq * 8);

  const unsigned short* Kp = qkv + bt_base + 1024 + h * 64;
  const unsigned short* Vp = qkv + bt_base + 2048 + h * 64;

  // K stage per-lane decomposition: row = 8-group + (l>>3); source chunk
  // pre-swizzled so LDS holds chunk_phys = chunk_logical ^ (row&7).
  const int krow = l >> 3;
  const int kcol = ((l & 7) ^ (l >> 3)) << 3;   // element offset of 16B chunk
  const int kx = (l15 & 7) << 3;                // read-side XOR (elements)

  // V stage (reg path): one row, 16 contiguous cols per thread
  const int vr = tid >> 2;            // 0..63
  const int vc0 = (tid & 3) << 4;     // 0,16,32,48

  f32x4 o_acc[4] = {};
  float m_j[4], l_j[4];
#pragma unroll
  for (int j = 0; j < 4; ++j) { m_j[j] = -1e30f; l_j[j] = 0.f; }

  bf16x8 v0, v1;

  // ---- prologue: stage tile 0 into buffer 0
  {
    gload_lds16(Kp + (size_t)(w * 8 + krow) * 3072 + kcol, &lK[(w * 8) * 64]);
    gload_lds16(Kp + (size_t)(32 + w * 8 + krow) * 3072 + kcol, &lK[(32 + w * 8) * 64]);
    const unsigned short* vb = Vp + (size_t)vr * 3072 + vc0;
    v0 = *(const bf16x8*)vb;
    v1 = *(const bf16x8*)(vb + 8);
#pragma unroll
    for (int i2 = 0; i2 < 8; ++i2) {
      lVt[(vc0 + i2) * 72 + vr] = (unsigned short)v0[i2];
      lVt[(vc0 + 8 + i2) * 72 + vr] = (unsigned short)v1[i2];
    }
  }
  __syncthreads();   // drains gload_lds (vmcnt) + lds writes

  for (int kt = 0; kt < 32; ++kt) {
    const int cur = kt & 1;
    const unsigned short* lKc = lK + cur * 4096;
    const unsigned short* lVc = lVt + cur * 4608;
    const bool stage = (kt < 31);

    // ---- issue next-tile staging before compute (latency hides under compute)
    if (stage) {
      const unsigned short* kb = Kp + (size_t)(kt + 1) * 64 * 3072;
      unsigned short* lKn = lK + (cur ^ 1) * 4096;
      gload_lds16(kb + (size_t)(w * 8 + krow) * 3072 + kcol, lKn + (w * 8) * 64);
      gload_lds16(kb + (size_t)(32 + w * 8 + krow) * 3072 + kcol, lKn + (32 + w * 8) * 64);
      const unsigned short* vb = Vp + (size_t)(kt + 1) * 64 * 3072 + (size_t)vr * 3072 + vc0;
      v0 = *(const bf16x8*)vb;
      v1 = *(const bf16x8*)(vb + 8);
    }

    // ---- S = Q K^T (swizzled K reads: 2-way banks, free)
    f32x4 s[4] = {};
#pragma unroll
    for (int ks = 0; ks < 2; ++ks) {
#pragma unroll
      for (int ni = 0; ni < 4; ++ni) {
        bf16x8 kf = *(const bf16x8*)&lKc[(ni * 16 + l15) * 64 + (((ks * 32 + lq * 8)) ^ kx)];
        s[ni] = __builtin_amdgcn_mfma_f32_16x16x32_bf16(qf[ks], kf, s[ni], 0, 0, 0);
      }
    }

    // ---- online softmax, 1/sqrt(64) folded in via fmaf
    float mx[4], rs[4], alpha[4];
#pragma unroll
    for (int j = 0; j < 4; ++j) {
      float m = -1e30f;
#pragma unroll
      for (int ni = 0; ni < 4; ++ni) m = fmaxf(m, s[ni][j]);
      mx[j] = m;
    }
#pragma unroll
    for (int j = 0; j < 4; ++j) {
#pragma unroll
      for (int off = 1; off < 16; off <<= 1)
        mx[j] = fmaxf(mx[j], __shfl_xor(mx[j], off));
      const float sm = mx[j] * 0.125f;
      const float mn = fmaxf(m_j[j], sm);
      alpha[j] = __expf(m_j[j] - mn);
      m_j[j] = mn;
      rs[j] = 0.f;
    }
#pragma unroll
    for (int ni = 0; ni < 4; ++ni) {
#pragma unroll
      for (int j = 0; j < 4; ++j) {
        const float p = __expf(__builtin_fmaf(s[ni][j], 0.125f, -m_j[j]));
        s[ni][j] = p;
        rs[j] += p;
      }
    }
#pragma unroll
    for (int j = 0; j < 4; ++j) {
#pragma unroll
      for (int off = 1; off < 16; off <<= 1)
        rs[j] += __shfl_xor(rs[j], off);
      l_j[j] = l_j[j] * alpha[j] + rs[j];
    }
#pragma unroll
    for (int df = 0; df < 4; ++df) {
      f32x4 t = o_acc[df];
      t[0] *= alpha[0]; t[1] *= alpha[1]; t[2] *= alpha[2]; t[3] *= alpha[3];
      o_acc[df] = t;
    }

    // ---- P -> LDS (per-wave region; same-wave in-order, no barrier needed)
#pragma unroll
    for (int ni = 0; ni < 4; ++ni)
#pragma unroll
      for (int j = 0; j < 4; ++j)
        lP[w * 1152 + (lq * 4 + j) * 72 + ni * 16 + l15] = f2bf(s[ni][j]);

    // ---- O += P V
#pragma unroll
    for (int ks = 0; ks < 2; ++ks) {
      bf16x8 pf = *(const bf16x8*)&lP[w * 1152 + l15 * 72 + ks * 32 + lq * 8];
#pragma unroll
      for (int df = 0; df < 4; ++df) {
        bf16x8 vf = *(const bf16x8*)&lVc[(df * 16 + l15) * 72 + ks * 32 + lq * 8];
        o_acc[df] = __builtin_amdgcn_mfma_f32_16x16x32_bf16(pf, vf, o_acc[df], 0, 0, 0);
      }
    }

    // ---- deferred V write into next buffer (its readers finished last iter)
    if (stage) {
      unsigned short* lVn = lVt + (cur ^ 1) * 4608;
#pragma unroll
      for (int i2 = 0; i2 < 8; ++i2) {
        lVn[(vc0 + i2) * 72 + vr] = (unsigned short)v0[i2];
        lVn[(vc0 + 8 + i2) * 72 + vr] = (unsigned short)v1[i2];
      }
    }
    __syncthreads();   // one barrier/iter: drains gload_lds + V writes
  }

  float inv[4];
#pragma unroll
  for (int j = 0; j < 4; ++j) inv[j] = 1.0f / l_j[j];
  unsigned short* op = aout +
      (size_t)(b * 2048 + qt * 64 + w * 16 + lq * 4) * 1024 + h * 64 + l15;
#pragma unroll
  for (int j = 0; j < 4; ++j)
#pragma unroll
    for (int df = 0; df < 4; ++df)
      op[(size_t)j * 1024 + df * 16] = f2bf(o_acc[df][j] * inv[j]);
}

// ---------------------------------------------------------------- launch
extern "C" void kernel_launch(void* const* d_in, const int* in_sizes, int n_in,
                              void* d_out, int out_size, void* d_ws, size_t ws_size,
                              hipStream_t stream) {
  const float* x     = (const float*)d_in[0];
  const float* w_qkv = (const float*)d_in[1];
  const float* b_qkv = (const float*)d_in[2];
  const float* w_out = (const float*)d_in[3];
  const float* b_out = (const float*)d_in[4];
  float* out = (float*)d_out;

  char* ws = (char*)d_ws;
  unsigned short* x_bf    = (unsigned short*)(ws);             // 16 MB
  unsigned short* wqkv_bf = (unsigned short*)(ws + 16777216);  // 6 MB
  unsigned short* wout_bf = (unsigned short*)(ws + 23068672);  // 2 MB
  unsigned short* qkv     = (unsigned short*)(ws + 25165824);  // 48 MB
  unsigned short* aout    = (unsigned short*)(ws + 75497472);  // 16 MB
  float2* cs              = (float2*)(ws + 92274688);          // 512 KB

  cast_f32_bf16<<<2097152 / 256, 256, 0, stream>>>(x, x_bf, 2097152);
  cast_f32_bf16<<<786432 / 256, 256, 0, stream>>>(w_qkv, wqkv_bf, 786432);
  cast_f32_bf16<<<262144 / 256, 256, 0, stream>>>(w_out, wout_bf, 262144);
  rope_table<<<65536 / 256, 256, 0, stream>>>(cs);

  // qkv = x @ w_qkv^T + b_qkv   (M=8192, N=3072, K=1024), bf16 out
  gemm_bt<1><<<64 * 24, 256, 0, stream>>>(x_bf, wqkv_bf, b_qkv, qkv,
                                          8192, 3072, 1024);
  rope_apply<<<4194304 / 256, 256, 0, stream>>>(qkv, cs);
  attn_fwd<<<2048, 256, 0, stream>>>(qkv, aout);
  // out = attn @ w_out^T + b_out (M=8192, N=1024, K=1024), f32 out
  gemm_bt<0><<<64 * 8, 256, 0, stream>>>(aout, wout_bf, b_out, out,
                                         8192, 1024, 1024);
}

// Round 3
// 248.997 us; speedup vs baseline: 1.6200x; 1.5185x over previous
//
#include <hip/hip_runtime.h>

typedef __attribute__((ext_vector_type(4))) float f32x4;
typedef __attribute__((ext_vector_type(16))) float f32x16;
typedef __attribute__((ext_vector_type(8))) short bf16x8;
typedef __attribute__((ext_vector_type(4))) unsigned u32x4;

__device__ __forceinline__ unsigned short f2bf(float f) {
  unsigned u = __float_as_uint(f);
  u += 0x7fff + ((u >> 16) & 1);   // round-to-nearest-even
  return (unsigned short)(u >> 16);
}
__device__ __forceinline__ float bf2f(unsigned short h) {
  return __uint_as_float(((unsigned)h) << 16);
}
__device__ __forceinline__ unsigned pk2(float a, float b) {
  return (unsigned)f2bf(a) | ((unsigned)f2bf(b) << 16);
}

__device__ __forceinline__ void gload_lds16(const void* g, void* lds) {
  __builtin_amdgcn_global_load_lds(
      (const __attribute__((address_space(1))) unsigned int*)g,
      (__attribute__((address_space(3))) unsigned int*)lds, 16, 0, 0);
}

// ---------------------------------------------------------------- cast f32->bf16
__global__ void cast_f32_bf16(const float* __restrict__ in,
                              unsigned short* __restrict__ out, int n4) {
  int i = blockIdx.x * blockDim.x + threadIdx.x;
  if (i >= n4) return;
  float4 v = ((const float4*)in)[i];
  ushort4 o;
  o.x = f2bf(v.x); o.y = f2bf(v.y); o.z = f2bf(v.z); o.w = f2bf(v.w);
  ((ushort4*)out)[i] = o;
}

// ---------------------------------------------------------------- RoPE cos/sin table
__global__ void rope_table(float2* __restrict__ cs) {
  int idx = blockIdx.x * blockDim.x + threadIdx.x;  // 2048*32
  if (idx >= 2048 * 32) return;
  int t = idx >> 5, i = idx & 31;
  float inv = powf(10000.0f, -(float)(2 * i) / 64.0f);
  float a = (float)t * inv;
  cs[idx] = make_float2(cosf(a), sinf(a));
}

// ---------------------------------------------------------------- RoPE apply (q,k in-place)
__global__ void rope_apply(unsigned short* __restrict__ qkv,
                           const float2* __restrict__ cs) {
  int idx = blockIdx.x * blockDim.x + threadIdx.x;  // B*T*H*32 = 4194304
  int i = idx & 31;
  int h = (idx >> 5) & 15;
  int t = (idx >> 9) & 2047;
  int b = idx >> 20;
  float2 v = cs[(t << 5) | i];
  size_t base = ((size_t)((b << 11) + t)) * 3072 + h * 64 + 2 * i;
#pragma unroll
  for (int part = 0; part < 2; ++part) {           // q then k
    unsigned short* p = qkv + base + part * 1024;
    unsigned pr = *(unsigned*)p;
    float e = bf2f((unsigned short)(pr & 0xffff));
    float o = bf2f((unsigned short)(pr >> 16));
    float ne = e * v.x - o * v.y;
    float no = e * v.y + o * v.x;
    *(unsigned*)p = (unsigned)f2bf(ne) | ((unsigned)f2bf(no) << 16);
  }
}

// ---------------------------------------------------------------- GEMM: C = A(MxK) * B(NxK)^T + bias
template <int OUT_BF16>
__global__ __launch_bounds__(256, 2) void gemm_bt(
    const unsigned short* __restrict__ A, const unsigned short* __restrict__ B,
    const float* __restrict__ bias, void* __restrict__ Cout,
    int M, int N, int K) {
  __shared__ unsigned short lA[128 * 64];
  __shared__ unsigned short lB[128 * 64];
  const int tiles_n = N >> 7;
  const int bm = blockIdx.x / tiles_n;
  const int bn = blockIdx.x % tiles_n;
  const int tid = threadIdx.x;
  const int w = tid >> 6, l = tid & 63;
  const int l15 = l & 15, lq = l >> 4;
  const int wm = (w >> 1) * 64, wn = (w & 1) * 64;
  const int m0 = bm << 7, n0 = bn << 7;
  const int arow = l >> 3;         // row within 8-row group
  const int acol = (l & 7) * 8;    // element col (8 bf16 = 16B)
  f32x4 acc[4][4] = {};

  for (int k0 = 0; k0 < K; k0 += 64) {
    __syncthreads();
#pragma unroll
    for (int it = 0; it < 4; ++it) {
      const int rb = it * 32 + w * 8;
      gload_lds16(A + (size_t)(m0 + rb + arow) * K + k0 + acol, &lA[rb * 64]);
      gload_lds16(B + (size_t)(n0 + rb + arow) * K + k0 + acol, &lB[rb * 64]);
    }
    __syncthreads();
#pragma unroll
    for (int ks = 0; ks < 2; ++ks) {
      bf16x8 af[4], bfr[4];
#pragma unroll
      for (int mi = 0; mi < 4; ++mi)
        af[mi] = *(const bf16x8*)&lA[(wm + mi * 16 + l15) * 64 + ks * 32 + lq * 8];
#pragma unroll
      for (int ni = 0; ni < 4; ++ni)
        bfr[ni] = *(const bf16x8*)&lB[(wn + ni * 16 + l15) * 64 + ks * 32 + lq * 8];
#pragma unroll
      for (int mi = 0; mi < 4; ++mi)
#pragma unroll
        for (int ni = 0; ni < 4; ++ni)
          acc[mi][ni] = __builtin_amdgcn_mfma_f32_16x16x32_bf16(
              af[mi], bfr[ni], acc[mi][ni], 0, 0, 0);
    }
  }

#pragma unroll
  for (int ni = 0; ni < 4; ++ni) {
    const int c = n0 + wn + ni * 16 + l15;
    const float bv = bias[c];
#pragma unroll
    for (int mi = 0; mi < 4; ++mi) {
#pragma unroll
      for (int j = 0; j < 4; ++j) {
        const int r = m0 + wm + mi * 16 + lq * 4 + j;
        const float v = acc[mi][ni][j] + bv;
        if (OUT_BF16)
          ((unsigned short*)Cout)[(size_t)r * N + c] = f2bf(v);
        else
          ((float*)Cout)[(size_t)r * N + c] = v;
      }
    }
  }
}

// ---------------------------------------------------------------- flash attention fwd
// v3: 32x32x16 MFMA, swapped QK^T (S^T), P fully in-register (pack + half-swap),
//     swizzled V^T writes, defer-max online softmax, QBLK=128 (4 waves x 32 q).
// qkv: [B*T][3072] bf16; aout: [B*T][1024] bf16
__global__ __launch_bounds__(256, 3) void attn_fwd(
    const unsigned short* __restrict__ qkv, unsigned short* __restrict__ aout) {
  __shared__ unsigned short lK[2 * 64 * 64];    // K tiles, chunk-XOR-swizzled
  __shared__ unsigned short lVt[2 * 64 * 72];   // V^T, stride 72, col^(row&0x30)

  // XCD-aware decode (1024 blocks = 8 xcd * 128)
  const int g = blockIdx.x;
  const int xcd = g & 7;
  const int j2 = g >> 3;                 // 0..127
  const int bh = ((j2 >> 4) << 3) + xcd; // 0..63
  const int qt = j2 & 15;
  const int h = bh & 15, b = bh >> 4;

  const int tid = threadIdx.x;
  const int w = tid >> 6, l = tid & 63;
  const int l31 = l & 31, hi = l >> 5;
  const int l7 = l & 7;

  const size_t bt_base = (size_t)(b * 2048) * 3072;
  const int qbase = qt * 128 + w * 32;

  // ---- Q fragments (B-operand: col=l&31 holds q-row; kk=(l>>5)*8+e), pre-scaled 1/8 (exact)
  const unsigned short* Qp =
      qkv + bt_base + (size_t)(qbase + l31) * 3072 + h * 64 + hi * 8;
  bf16x8 qf[4];
#pragma unroll
  for (int s = 0; s < 4; ++s) {
    bf16x8 q = *(const bf16x8*)(Qp + 16 * s);
#pragma unroll
    for (int e = 0; e < 8; ++e)
      q[e] = (short)f2bf(bf2f((unsigned short)q[e]) * 0.125f);
    qf[s] = q;
  }

  const unsigned short* Kp = qkv + bt_base + 1024 + h * 64;
  const unsigned short* Vp = qkv + bt_base + 2048 + h * 64;

  // K stage: row = group + (l>>3), chunk pre-swizzled so phys = logical ^ (row&7)
  const int krow = l >> 3;
  const int kcol = ((l & 7) ^ (l >> 3)) << 3;

  // V stage: thread reads V[row=vr][cols vc0..vc0+15], writes V^T swizzled
  const int vr = tid >> 2;
  const int vc0 = (tid & 3) << 4;

  f32x16 o0 = {}, o1 = {};
  float m_run = -1e30f, lsum = 0.f;
  bf16x8 v0, v1;

  // ---- prologue: stage tile 0 into buffer 0
  {
    gload_lds16(Kp + (size_t)(w * 8 + krow) * 3072 + kcol, &lK[(w * 8) * 64]);
    gload_lds16(Kp + (size_t)(32 + w * 8 + krow) * 3072 + kcol, &lK[(32 + w * 8) * 64]);
    const unsigned short* vb = Vp + (size_t)vr * 3072 + vc0;
    v0 = *(const bf16x8*)vb;
    v1 = *(const bf16x8*)(vb + 8);
#pragma unroll
    for (int i2 = 0; i2 < 8; ++i2) {
      lVt[(vc0 + i2) * 72 + (vr ^ vc0)] = (unsigned short)v0[i2];
      lVt[(vc0 + 8 + i2) * 72 + (vr ^ vc0)] = (unsigned short)v1[i2];
    }
  }
  __syncthreads();

  for (int kt = 0; kt < 32; ++kt) {
    const int cur = kt & 1;
    const unsigned short* lKc = lK + cur * 4096;
    const unsigned short* lVc = lVt + cur * 4608;
    const bool stage = (kt < 31);

    // ---- issue next-tile staging early (hides HBM latency under compute)
    if (stage) {
      const unsigned short* kb = Kp + (size_t)(kt + 1) * 64 * 3072;
      unsigned short* lKn = lK + (cur ^ 1) * 4096;
      gload_lds16(kb + (size_t)(w * 8 + krow) * 3072 + kcol, lKn + (w * 8) * 64);
      gload_lds16(kb + (size_t)(32 + w * 8 + krow) * 3072 + kcol, lKn + (32 + w * 8) * 64);
      const unsigned short* vb = Vp + (size_t)(kt + 1) * 64 * 3072 + (size_t)vr * 3072 + vc0;
      v0 = *(const bf16x8*)vb;
      v1 = *(const bf16x8*)(vb + 8);
    }

    // ---- S^T = K * Q  (D[row=k][col=q]); sa[kt2] covers k = kt2*32 + crow(r,hi)
    f32x16 sa[2] = {{}, {}};
#pragma unroll
    for (int kt2 = 0; kt2 < 2; ++kt2) {
#pragma unroll
      for (int s = 0; s < 4; ++s) {
        bf16x8 kf = *(const bf16x8*)&lKc[(kt2 * 32 + l31) * 64 + (((2 * s + hi) ^ l7) << 3)];
        sa[kt2] = __builtin_amdgcn_mfma_f32_32x32x16_bf16(kf, qf[s], sa[kt2], 0, 0, 0);
      }
    }

    // ---- online softmax (defer-max, THR=8); row q = l&31 is lane-local
    float pmax = -1e30f;
#pragma unroll
    for (int r = 0; r < 16; ++r) {
      pmax = fmaxf(pmax, sa[0][r]);
      pmax = fmaxf(pmax, sa[1][r]);
    }
    pmax = fmaxf(pmax, __shfl_xor(pmax, 32));
    if (!__all(pmax <= m_run + 8.0f)) {
      const float mn = fmaxf(m_run, pmax);
      const float alpha = __expf(m_run - mn);
      m_run = mn;
      lsum *= alpha;
#pragma unroll
      for (int r = 0; r < 16; ++r) {
        const float ar = __shfl(alpha, (r & 3) + 8 * (r >> 2) + 4 * hi);
        o0[r] *= ar;
        o1[r] *= ar;
      }
    }
    float rs = 0.f;
#pragma unroll
    for (int r = 0; r < 16; ++r) {
      const float p0 = __expf(sa[0][r] - m_run);
      const float p1 = __expf(sa[1][r] - m_run);
      sa[0][r] = p0;
      sa[1][r] = p1;
      rs += p0 + p1;
    }
    rs += __shfl_xor(rs, 32);
    lsum += rs;

    // ---- P -> A-operand frags in-register (pack pairs, exchange halves), then PV
#pragma unroll
    for (int ks = 0; ks < 4; ++ks) {
      const int kt2 = ks >> 1, k2 = (ks & 1) * 8;
      const unsigned xa = pk2(sa[kt2][k2 + 0], sa[kt2][k2 + 1]);
      const unsigned xb = pk2(sa[kt2][k2 + 2], sa[kt2][k2 + 3]);
      const unsigned ya = pk2(sa[kt2][k2 + 4], sa[kt2][k2 + 5]);
      const unsigned yb = pk2(sa[kt2][k2 + 6], sa[kt2][k2 + 7]);
      const unsigned xas = (unsigned)__shfl_xor((int)xa, 32);
      const unsigned xbs = (unsigned)__shfl_xor((int)xb, 32);
      const unsigned yas = (unsigned)__shfl_xor((int)ya, 32);
      const unsigned ybs = (unsigned)__shfl_xor((int)yb, 32);
      u32x4 pw;
      pw[0] = hi ? yas : xa;
      pw[1] = hi ? ybs : xb;
      pw[2] = hi ? ya : xas;
      pw[3] = hi ? yb : xbs;
      const bf16x8 pa = __builtin_bit_cast(bf16x8, pw);
#pragma unroll
      for (int nd = 0; nd < 2; ++nd) {
        const int vrow = nd * 32 + l31;
        const bf16x8 vf = *(const bf16x8*)
            &lVc[vrow * 72 + ((16 * ks + 8 * hi) ^ (vrow & 0x30))];
        if (nd == 0)
          o0 = __builtin_amdgcn_mfma_f32_32x32x16_bf16(pa, vf, o0, 0, 0, 0);
        else
          o1 = __builtin_amdgcn_mfma_f32_32x32x16_bf16(pa, vf, o1, 0, 0, 0);
      }
    }

    // ---- deferred V^T write into next buffer
    if (stage) {
      unsigned short* lVn = lVt + (cur ^ 1) * 4608;
#pragma unroll
      for (int i2 = 0; i2 < 8; ++i2) {
        lVn[(vc0 + i2) * 72 + (vr ^ vc0)] = (unsigned short)v0[i2];
        lVn[(vc0 + 8 + i2) * 72 + (vr ^ vc0)] = (unsigned short)v1[i2];
      }
    }
    __syncthreads();
  }

  // ---- epilogue: O[q][d] / l[q]; lane holds rows crow(r,hi), cols d = nd*32 + l31
  const float linv = 1.0f / lsum;
#pragma unroll
  for (int r = 0; r < 16; ++r) {
    const int crow = (r & 3) + 8 * (r >> 2) + 4 * hi;
    const float lr = __shfl(linv, crow);
    unsigned short* orow =
        aout + (size_t)(b * 2048 + qbase + crow) * 1024 + h * 64 + l31;
    orow[0] = f2bf(o0[r] * lr);
    orow[32] = f2bf(o1[r] * lr);
  }
}

// ---------------------------------------------------------------- launch
extern "C" void kernel_launch(void* const* d_in, const int* in_sizes, int n_in,
                              void* d_out, int out_size, void* d_ws, size_t ws_size,
                              hipStream_t stream) {
  const float* x     = (const float*)d_in[0];
  const float* w_qkv = (const float*)d_in[1];
  const float* b_qkv = (const float*)d_in[2];
  const float* w_out = (const float*)d_in[3];
  const float* b_out = (const float*)d_in[4];
  float* out = (float*)d_out;

  char* ws = (char*)d_ws;
  unsigned short* x_bf    = (unsigned short*)(ws);             // 16 MB
  unsigned short* wqkv_bf = (unsigned short*)(ws + 16777216);  // 6 MB
  unsigned short* wout_bf = (unsigned short*)(ws + 23068672);  // 2 MB
  unsigned short* qkv     = (unsigned short*)(ws + 25165824);  // 48 MB
  unsigned short* aout    = (unsigned short*)(ws + 75497472);  // 16 MB
  float2* cs              = (float2*)(ws + 92274688);          // 512 KB

  cast_f32_bf16<<<2097152 / 256, 256, 0, stream>>>(x, x_bf, 2097152);
  cast_f32_bf16<<<786432 / 256, 256, 0, stream>>>(w_qkv, wqkv_bf, 786432);
  cast_f32_bf16<<<262144 / 256, 256, 0, stream>>>(w_out, wout_bf, 262144);
  rope_table<<<65536 / 256, 256, 0, stream>>>(cs);

  // qkv = x @ w_qkv^T + b_qkv   (M=8192, N=3072, K=1024), bf16 out
  gemm_bt<1><<<64 * 24, 256, 0, stream>>>(x_bf, wqkv_bf, b_qkv, qkv,
                                          8192, 3072, 1024);
  rope_apply<<<4194304 / 256, 256, 0, stream>>>(qkv, cs);
  attn_fwd<<<1024, 256, 0, stream>>>(qkv, aout);
  // out = attn @ w_out^T + b_out (M=8192, N=1024, K=1024), f32 out
  gemm_bt<0><<<64 * 8, 256, 0, stream>>>(aout, wout_bf, b_out, out,
                                         8192, 1024, 1024);
}

// Round 4
// 241.777 us; speedup vs baseline: 1.6684x; 1.0299x over previous
//
#include <hip/hip_runtime.h>

typedef __attribute__((ext_vector_type(4))) float f32x4;
typedef __attribute__((ext_vector_type(16))) float f32x16;
typedef __attribute__((ext_vector_type(8))) short bf16x8;
typedef __attribute__((ext_vector_type(4))) unsigned u32x4;

__device__ __forceinline__ unsigned short f2bf(float f) {
  unsigned u = __float_as_uint(f);
  u += 0x7fff + ((u >> 16) & 1);   // round-to-nearest-even
  return (unsigned short)(u >> 16);
}
__device__ __forceinline__ float bf2f(unsigned short h) {
  return __uint_as_float(((unsigned)h) << 16);
}

__device__ __forceinline__ void gload_lds16(const void* g, void* lds) {
  __builtin_amdgcn_global_load_lds(
      (const __attribute__((address_space(1))) unsigned int*)g,
      (__attribute__((address_space(3))) unsigned int*)lds, 16, 0, 0);
}

// ---------------------------------------------------------------- cast f32->bf16
__global__ void cast_f32_bf16(const float* __restrict__ in,
                              unsigned short* __restrict__ out, int n4) {
  int i = blockIdx.x * blockDim.x + threadIdx.x;
  if (i >= n4) return;
  float4 v = ((const float4*)in)[i];
  ushort4 o;
  o.x = f2bf(v.x); o.y = f2bf(v.y); o.z = f2bf(v.z); o.w = f2bf(v.w);
  ((ushort4*)out)[i] = o;
}

// ---------------------------------------------------------------- RoPE cos/sin table
__global__ void rope_table(float2* __restrict__ cs) {
  int idx = blockIdx.x * blockDim.x + threadIdx.x;  // 2048*32
  if (idx >= 2048 * 32) return;
  int t = idx >> 5, i = idx & 31;
  float inv = powf(10000.0f, -(float)(2 * i) / 64.0f);
  float a = (float)t * inv;
  cs[idx] = make_float2(cosf(a), sinf(a));
}

// ---------------------------------------------------------------- GEMM: C = A(MxK) * B(NxK)^T + bias
// ROPE=1: fuse RoPE rotation into epilogue for columns < 2048 (q,k heads).
template <int OUT_BF16, int ROPE>
__global__ __launch_bounds__(256, 2) void gemm_bt(
    const unsigned short* __restrict__ A, const unsigned short* __restrict__ B,
    const float* __restrict__ bias, void* __restrict__ Cout,
    const float2* __restrict__ cs, int M, int N, int K) {
  __shared__ unsigned short lA[128 * 64];
  __shared__ unsigned short lB[128 * 64];
  const int tiles_n = N >> 7;
  const int bm = blockIdx.x / tiles_n;
  const int bn = blockIdx.x % tiles_n;
  const int tid = threadIdx.x;
  const int w = tid >> 6, l = tid & 63;
  const int l15 = l & 15, lq = l >> 4;
  const int wm = (w >> 1) * 64, wn = (w & 1) * 64;
  const int m0 = bm << 7, n0 = bn << 7;
  const int arow = l >> 3;         // row within 8-row group
  const int acol = (l & 7) * 8;    // element col (8 bf16 = 16B)
  f32x4 acc[4][4] = {};

  for (int k0 = 0; k0 < K; k0 += 64) {
    __syncthreads();
#pragma unroll
    for (int it = 0; it < 4; ++it) {
      const int rb = it * 32 + w * 8;
      gload_lds16(A + (size_t)(m0 + rb + arow) * K + k0 + acol, &lA[rb * 64]);
      gload_lds16(B + (size_t)(n0 + rb + arow) * K + k0 + acol, &lB[rb * 64]);
    }
    __syncthreads();
#pragma unroll
    for (int ks = 0; ks < 2; ++ks) {
      bf16x8 af[4], bfr[4];
#pragma unroll
      for (int mi = 0; mi < 4; ++mi)
        af[mi] = *(const bf16x8*)&lA[(wm + mi * 16 + l15) * 64 + ks * 32 + lq * 8];
#pragma unroll
      for (int ni = 0; ni < 4; ++ni)
        bfr[ni] = *(const bf16x8*)&lB[(wn + ni * 16 + l15) * 64 + ks * 32 + lq * 8];
#pragma unroll
      for (int mi = 0; mi < 4; ++mi)
#pragma unroll
        for (int ni = 0; ni < 4; ++ni)
          acc[mi][ni] = __builtin_amdgcn_mfma_f32_16x16x32_bf16(
              af[mi], bfr[ni], acc[mi][ni], 0, 0, 0);
    }
  }

#pragma unroll
  for (int ni = 0; ni < 4; ++ni) {
    const int c = n0 + wn + ni * 16 + l15;
    const float bv = bias[c];
    const bool rope_col = ROPE && (c < 2048);   // tile-uniform (128 | 2048)
    const int ih = (c & 63) >> 1;
    const int odd = c & 1;
#pragma unroll
    for (int mi = 0; mi < 4; ++mi) {
#pragma unroll
      for (int j = 0; j < 4; ++j) {
        const int r = m0 + wm + mi * 16 + lq * 4 + j;
        float v = acc[mi][ni][j] + bv;
        if (rope_col) {
          const float other = __shfl_xor(v, 1);       // pair partner (c^1)
          const float2 cssn = cs[(r & 2047) * 32 + ih];
          // even col: te*cos - to*sin ; odd col: te*sin + to*cos
          v = odd ? (other * cssn.y + v * cssn.x)
                  : (v * cssn.x - other * cssn.y);
        }
        if (OUT_BF16)
          ((unsigned short*)Cout)[(size_t)r * N + c] = f2bf(v);
        else
          ((float*)Cout)[(size_t)r * N + c] = v;
      }
    }
  }
}

// ---------------------------------------------------------------- flash attention fwd
// v4: v3 + cvt_pk_bf16 + permlane32_swap in-register P-pack (T12).
// qkv: [B*T][3072] bf16; aout: [B*T][1024] bf16
__global__ __launch_bounds__(256, 3) void attn_fwd(
    const unsigned short* __restrict__ qkv, unsigned short* __restrict__ aout) {
  __shared__ unsigned short lK[2 * 64 * 64];    // K tiles, chunk-XOR-swizzled
  __shared__ unsigned short lVt[2 * 64 * 72];   // V^T, stride 72, col^(row&0x30)

  // XCD-aware decode (1024 blocks = 8 xcd * 128)
  const int g = blockIdx.x;
  const int xcd = g & 7;
  const int j2 = g >> 3;                 // 0..127
  const int bh = ((j2 >> 4) << 3) + xcd; // 0..63
  const int qt = j2 & 15;
  const int h = bh & 15, b = bh >> 4;

  const int tid = threadIdx.x;
  const int w = tid >> 6, l = tid & 63;
  const int l31 = l & 31, hi = l >> 5;
  const int l7 = l & 7;

  const size_t bt_base = (size_t)(b * 2048) * 3072;
  const int qbase = qt * 128 + w * 32;

  // ---- Q fragments (B-operand: col=l&31 holds q-row; kk=(l>>5)*8+e), pre-scaled 1/8 (exact)
  const unsigned short* Qp =
      qkv + bt_base + (size_t)(qbase + l31) * 3072 + h * 64 + hi * 8;
  bf16x8 qf[4];
#pragma unroll
  for (int s = 0; s < 4; ++s) {
    bf16x8 q = *(const bf16x8*)(Qp + 16 * s);
#pragma unroll
    for (int e = 0; e < 8; ++e)
      q[e] = (short)f2bf(bf2f((unsigned short)q[e]) * 0.125f);
    qf[s] = q;
  }

  const unsigned short* Kp = qkv + bt_base + 1024 + h * 64;
  const unsigned short* Vp = qkv + bt_base + 2048 + h * 64;

  // K stage: row = group + (l>>3), chunk pre-swizzled so phys = logical ^ (row&7)
  const int krow = l >> 3;
  const int kcol = ((l & 7) ^ (l >> 3)) << 3;

  // V stage: thread reads V[row=vr][cols vc0..vc0+15], writes V^T swizzled
  const int vr = tid >> 2;
  const int vc0 = (tid & 3) << 4;

  f32x16 o0 = {}, o1 = {};
  float m_run = -1e30f, lsum = 0.f;
  bf16x8 v0, v1;

  // ---- prologue: stage tile 0 into buffer 0
  {
    gload_lds16(Kp + (size_t)(w * 8 + krow) * 3072 + kcol, &lK[(w * 8) * 64]);
    gload_lds16(Kp + (size_t)(32 + w * 8 + krow) * 3072 + kcol, &lK[(32 + w * 8) * 64]);
    const unsigned short* vb = Vp + (size_t)vr * 3072 + vc0;
    v0 = *(const bf16x8*)vb;
    v1 = *(const bf16x8*)(vb + 8);
#pragma unroll
    for (int i2 = 0; i2 < 8; ++i2) {
      lVt[(vc0 + i2) * 72 + (vr ^ vc0)] = (unsigned short)v0[i2];
      lVt[(vc0 + 8 + i2) * 72 + (vr ^ vc0)] = (unsigned short)v1[i2];
    }
  }
  __syncthreads();

  for (int kt = 0; kt < 32; ++kt) {
    const int cur = kt & 1;
    const unsigned short* lKc = lK + cur * 4096;
    const unsigned short* lVc = lVt + cur * 4608;
    const bool stage = (kt < 31);

    // ---- issue next-tile staging early (hides HBM latency under compute)
    if (stage) {
      const unsigned short* kb = Kp + (size_t)(kt + 1) * 64 * 3072;
      unsigned short* lKn = lK + (cur ^ 1) * 4096;
      gload_lds16(kb + (size_t)(w * 8 + krow) * 3072 + kcol, lKn + (w * 8) * 64);
      gload_lds16(kb + (size_t)(32 + w * 8 + krow) * 3072 + kcol, lKn + (32 + w * 8) * 64);
      const unsigned short* vb = Vp + (size_t)(kt + 1) * 64 * 3072 + (size_t)vr * 3072 + vc0;
      v0 = *(const bf16x8*)vb;
      v1 = *(const bf16x8*)(vb + 8);
    }

    // ---- S^T = K * Q  (D[row=k][col=q]); sa[kt2] covers k = kt2*32 + crow(r,hi)
    f32x16 sa[2] = {{}, {}};
#pragma unroll
    for (int kt2 = 0; kt2 < 2; ++kt2) {
#pragma unroll
      for (int s = 0; s < 4; ++s) {
        bf16x8 kf = *(const bf16x8*)&lKc[(kt2 * 32 + l31) * 64 + (((2 * s + hi) ^ l7) << 3)];
        sa[kt2] = __builtin_amdgcn_mfma_f32_32x32x16_bf16(kf, qf[s], sa[kt2], 0, 0, 0);
      }
    }

    // ---- online softmax (defer-max, THR=8); row q = l&31 is lane-local
    float pmax = -1e30f;
#pragma unroll
    for (int r = 0; r < 16; ++r) {
      pmax = fmaxf(pmax, sa[0][r]);
      pmax = fmaxf(pmax, sa[1][r]);
    }
    pmax = fmaxf(pmax, __shfl_xor(pmax, 32));
    if (!__all(pmax <= m_run + 8.0f)) {
      const float mn = fmaxf(m_run, pmax);
      const float alpha = __expf(m_run - mn);
      m_run = mn;
      lsum *= alpha;
#pragma unroll
      for (int r = 0; r < 16; ++r) {
        const float ar = __shfl(alpha, (r & 3) + 8 * (r >> 2) + 4 * hi);
        o0[r] *= ar;
        o1[r] *= ar;
      }
    }
    float rs = 0.f;
#pragma unroll
    for (int r = 0; r < 16; ++r) {
      const float p0 = __expf(sa[0][r] - m_run);
      const float p1 = __expf(sa[1][r] - m_run);
      sa[0][r] = p0;
      sa[1][r] = p1;
      rs += p0 + p1;
    }
    rs += __shfl_xor(rs, 32);
    lsum += rs;

    // ---- P -> A-operand frags fully in-register: cvt_pk pairs + permlane32_swap
    //      (new xa = lo:xa | hi:ya[l^32]; new ya = lo:xa[l^32] | hi:ya)
#pragma unroll
    for (int ks = 0; ks < 4; ++ks) {
      const int kt2 = ks >> 1, k2 = (ks & 1) * 8;
      unsigned xa, xb, ya, yb;
      asm("v_cvt_pk_bf16_f32 %0, %1, %2"
          : "=v"(xa) : "v"(sa[kt2][k2 + 0]), "v"(sa[kt2][k2 + 1]));
      asm("v_cvt_pk_bf16_f32 %0, %1, %2"
          : "=v"(xb) : "v"(sa[kt2][k2 + 2]), "v"(sa[kt2][k2 + 3]));
      asm("v_cvt_pk_bf16_f32 %0, %1, %2"
          : "=v"(ya) : "v"(sa[kt2][k2 + 4]), "v"(sa[kt2][k2 + 5]));
      asm("v_cvt_pk_bf16_f32 %0, %1, %2"
          : "=v"(yb) : "v"(sa[kt2][k2 + 6]), "v"(sa[kt2][k2 + 7]));
      asm("v_permlane32_swap_b32 %0, %1" : "+v"(xa), "+v"(ya));
      asm("v_permlane32_swap_b32 %0, %1" : "+v"(xb), "+v"(yb));
      u32x4 pw;
      pw[0] = xa; pw[1] = xb; pw[2] = ya; pw[3] = yb;
      const bf16x8 pa = __builtin_bit_cast(bf16x8, pw);
#pragma unroll
      for (int nd = 0; nd < 2; ++nd) {
        const int vrow = nd * 32 + l31;
        const bf16x8 vf = *(const bf16x8*)
            &lVc[vrow * 72 + ((16 * ks + 8 * hi) ^ (vrow & 0x30))];
        if (nd == 0)
          o0 = __builtin_amdgcn_mfma_f32_32x32x16_bf16(pa, vf, o0, 0, 0, 0);
        else
          o1 = __builtin_amdgcn_mfma_f32_32x32x16_bf16(pa, vf, o1, 0, 0, 0);
      }
    }

    // ---- deferred V^T write into next buffer
    if (stage) {
      unsigned short* lVn = lVt + (cur ^ 1) * 4608;
#pragma unroll
      for (int i2 = 0; i2 < 8; ++i2) {
        lVn[(vc0 + i2) * 72 + (vr ^ vc0)] = (unsigned short)v0[i2];
        lVn[(vc0 + 8 + i2) * 72 + (vr ^ vc0)] = (unsigned short)v1[i2];
      }
    }
    __syncthreads();
  }

  // ---- epilogue: O[q][d] / l[q]; lane holds rows crow(r,hi), cols d = nd*32 + l31
  const float linv = 1.0f / lsum;
#pragma unroll
  for (int r = 0; r < 16; ++r) {
    const int crow = (r & 3) + 8 * (r >> 2) + 4 * hi;
    const float lr = __shfl(linv, crow);
    unsigned short* orow =
        aout + (size_t)(b * 2048 + qbase + crow) * 1024 + h * 64 + l31;
    orow[0] = f2bf(o0[r] * lr);
    orow[32] = f2bf(o1[r] * lr);
  }
}

// ---------------------------------------------------------------- launch
extern "C" void kernel_launch(void* const* d_in, const int* in_sizes, int n_in,
                              void* d_out, int out_size, void* d_ws, size_t ws_size,
                              hipStream_t stream) {
  const float* x     = (const float*)d_in[0];
  const float* w_qkv = (const float*)d_in[1];
  const float* b_qkv = (const float*)d_in[2];
  const float* w_out = (const float*)d_in[3];
  const float* b_out = (const float*)d_in[4];
  float* out = (float*)d_out;

  char* ws = (char*)d_ws;
  unsigned short* x_bf    = (unsigned short*)(ws);             // 16 MB
  unsigned short* wqkv_bf = (unsigned short*)(ws + 16777216);  // 6 MB
  unsigned short* wout_bf = (unsigned short*)(ws + 23068672);  // 2 MB
  unsigned short* qkv     = (unsigned short*)(ws + 25165824);  // 48 MB
  unsigned short* aout    = (unsigned short*)(ws + 75497472);  // 16 MB
  float2* cs              = (float2*)(ws + 92274688);          // 512 KB

  cast_f32_bf16<<<2097152 / 256, 256, 0, stream>>>(x, x_bf, 2097152);
  cast_f32_bf16<<<786432 / 256, 256, 0, stream>>>(w_qkv, wqkv_bf, 786432);
  cast_f32_bf16<<<262144 / 256, 256, 0, stream>>>(w_out, wout_bf, 262144);
  rope_table<<<65536 / 256, 256, 0, stream>>>(cs);

  // qkv = x @ w_qkv^T + b_qkv, RoPE fused into epilogue for q,k columns
  gemm_bt<1, 1><<<64 * 24, 256, 0, stream>>>(x_bf, wqkv_bf, b_qkv, qkv, cs,
                                             8192, 3072, 1024);
  attn_fwd<<<1024, 256, 0, stream>>>(qkv, aout);
  // out = attn @ w_out^T + b_out (M=8192, N=1024, K=1024), f32 out
  gemm_bt<0, 0><<<64 * 8, 256, 0, stream>>>(aout, wout_bf, b_out, out, nullptr,
                                            8192, 1024, 1024);
}

// Round 5
// 229.999 us; speedup vs baseline: 1.7538x; 1.0512x over previous
//
#include <hip/hip_runtime.h>

typedef __attribute__((ext_vector_type(4))) float f32x4;
typedef __attribute__((ext_vector_type(16))) float f32x16;
typedef __attribute__((ext_vector_type(8))) short bf16x8;
typedef __attribute__((ext_vector_type(4))) unsigned u32x4;

__device__ __forceinline__ unsigned short f2bf(float f) {
  unsigned u = __float_as_uint(f);
  u += 0x7fff + ((u >> 16) & 1);   // round-to-nearest-even
  return (unsigned short)(u >> 16);
}
__device__ __forceinline__ float bf2f(unsigned short h) {
  return __uint_as_float(((unsigned)h) << 16);
}

__device__ __forceinline__ void gload_lds16(const void* g, void* lds) {
  __builtin_amdgcn_global_load_lds(
      (const __attribute__((address_space(1))) unsigned int*)g,
      (__attribute__((address_space(3))) unsigned int*)lds, 16, 0, 0);
}

// ---------------------------------------------------------------- cast f32->bf16
__global__ void cast_f32_bf16(const float* __restrict__ in,
                              unsigned short* __restrict__ out, int n4) {
  int i = blockIdx.x * blockDim.x + threadIdx.x;
  if (i >= n4) return;
  float4 v = ((const float4*)in)[i];
  ushort4 o;
  o.x = f2bf(v.x); o.y = f2bf(v.y); o.z = f2bf(v.z); o.w = f2bf(v.w);
  ((ushort4*)out)[i] = o;
}

// ---------------------------------------------------------------- RoPE cos/sin table
__global__ void rope_table(float2* __restrict__ cs) {
  int idx = blockIdx.x * blockDim.x + threadIdx.x;  // 2048*32
  if (idx >= 2048 * 32) return;
  int t = idx >> 5, i = idx & 31;
  float inv = powf(10000.0f, -(float)(2 * i) / 64.0f);
  float a = (float)t * inv;
  cs[idx] = make_float2(cosf(a), sinf(a));
}

// ---------------------------------------------------------------- RoPE apply (q,k in-place)
__global__ void rope_apply(unsigned short* __restrict__ qkv,
                           const float2* __restrict__ cs) {
  int idx = blockIdx.x * blockDim.x + threadIdx.x;  // B*T*H*32 = 4194304
  int i = idx & 31;
  int h = (idx >> 5) & 15;
  int t = (idx >> 9) & 2047;
  int b = idx >> 20;
  float2 v = cs[(t << 5) | i];
  size_t base = ((size_t)((b << 11) + t)) * 3072 + h * 64 + 2 * i;
#pragma unroll
  for (int part = 0; part < 2; ++part) {           // q then k
    unsigned short* p = qkv + base + part * 1024;
    unsigned pr = *(unsigned*)p;
    float e = bf2f((unsigned short)(pr & 0xffff));
    float o = bf2f((unsigned short)(pr >> 16));
    float ne = e * v.x - o * v.y;
    float no = e * v.y + o * v.x;
    *(unsigned*)p = (unsigned)f2bf(ne) | ((unsigned)f2bf(no) << 16);
  }
}

// ---------------------------------------------------------------- GEMM: C = A(MxK) * B(NxK)^T + bias
template <int OUT_BF16>
__global__ __launch_bounds__(256, 2) void gemm_bt(
    const unsigned short* __restrict__ A, const unsigned short* __restrict__ B,
    const float* __restrict__ bias, void* __restrict__ Cout,
    int M, int N, int K) {
  __shared__ unsigned short lA[128 * 64];
  __shared__ unsigned short lB[128 * 64];
  const int tiles_n = N >> 7;
  const int bm = blockIdx.x / tiles_n;
  const int bn = blockIdx.x % tiles_n;
  const int tid = threadIdx.x;
  const int w = tid >> 6, l = tid & 63;
  const int l15 = l & 15, lq = l >> 4;
  const int wm = (w >> 1) * 64, wn = (w & 1) * 64;
  const int m0 = bm << 7, n0 = bn << 7;
  const int arow = l >> 3;         // row within 8-row group
  const int acol = (l & 7) * 8;    // element col (8 bf16 = 16B)
  f32x4 acc[4][4] = {};

  for (int k0 = 0; k0 < K; k0 += 64) {
    __syncthreads();
#pragma unroll
    for (int it = 0; it < 4; ++it) {
      const int rb = it * 32 + w * 8;
      gload_lds16(A + (size_t)(m0 + rb + arow) * K + k0 + acol, &lA[rb * 64]);
      gload_lds16(B + (size_t)(n0 + rb + arow) * K + k0 + acol, &lB[rb * 64]);
    }
    __syncthreads();
#pragma unroll
    for (int ks = 0; ks < 2; ++ks) {
      bf16x8 af[4], bfr[4];
#pragma unroll
      for (int mi = 0; mi < 4; ++mi)
        af[mi] = *(const bf16x8*)&lA[(wm + mi * 16 + l15) * 64 + ks * 32 + lq * 8];
#pragma unroll
      for (int ni = 0; ni < 4; ++ni)
        bfr[ni] = *(const bf16x8*)&lB[(wn + ni * 16 + l15) * 64 + ks * 32 + lq * 8];
#pragma unroll
      for (int mi = 0; mi < 4; ++mi)
#pragma unroll
        for (int ni = 0; ni < 4; ++ni)
          acc[mi][ni] = __builtin_amdgcn_mfma_f32_16x16x32_bf16(
              af[mi], bfr[ni], acc[mi][ni], 0, 0, 0);
    }
  }

#pragma unroll
  for (int ni = 0; ni < 4; ++ni) {
    const int c = n0 + wn + ni * 16 + l15;
    const float bv = bias[c];
#pragma unroll
    for (int mi = 0; mi < 4; ++mi) {
#pragma unroll
      for (int j = 0; j < 4; ++j) {
        const int r = m0 + wm + mi * 16 + lq * 4 + j;
        const float v = acc[mi][ni][j] + bv;
        if (OUT_BF16)
          ((unsigned short*)Cout)[(size_t)r * N + c] = f2bf(v);
        else
          ((float*)Cout)[(size_t)r * N + c] = v;
      }
    }
  }
}

// ---------------------------------------------------------------- flash attention fwd
// v5: v4 + VALU diet (v_max3 chain, exp2-direct via fma, paired rs) + setprio
//     around MFMA clusters.
// qkv: [B*T][3072] bf16; aout: [B*T][1024] bf16
__global__ __launch_bounds__(256, 3) void attn_fwd(
    const unsigned short* __restrict__ qkv, unsigned short* __restrict__ aout) {
  __shared__ unsigned short lK[2 * 64 * 64];    // K tiles, chunk-XOR-swizzled
  __shared__ unsigned short lVt[2 * 64 * 72];   // V^T, stride 72, col^(row&0x30)

  // XCD-aware decode (1024 blocks = 8 xcd * 128)
  const int g = blockIdx.x;
  const int xcd = g & 7;
  const int j2 = g >> 3;                 // 0..127
  const int bh = ((j2 >> 4) << 3) + xcd; // 0..63
  const int qt = j2 & 15;
  const int h = bh & 15, b = bh >> 4;

  const int tid = threadIdx.x;
  const int w = tid >> 6, l = tid & 63;
  const int l31 = l & 31, hi = l >> 5;
  const int l7 = l & 7;

  const size_t bt_base = (size_t)(b * 2048) * 3072;
  const int qbase = qt * 128 + w * 32;

  // ---- Q fragments (B-operand: col=l&31 holds q-row; kk=(l>>5)*8+e), pre-scaled 1/8 (exact)
  const unsigned short* Qp =
      qkv + bt_base + (size_t)(qbase + l31) * 3072 + h * 64 + hi * 8;
  bf16x8 qf[4];
#pragma unroll
  for (int s = 0; s < 4; ++s) {
    bf16x8 q = *(const bf16x8*)(Qp + 16 * s);
#pragma unroll
    for (int e = 0; e < 8; ++e)
      q[e] = (short)f2bf(bf2f((unsigned short)q[e]) * 0.125f);
    qf[s] = q;
  }

  const unsigned short* Kp = qkv + bt_base + 1024 + h * 64;
  const unsigned short* Vp = qkv + bt_base + 2048 + h * 64;

  // K stage: row = group + (l>>3), chunk pre-swizzled so phys = logical ^ (row&7)
  const int krow = l >> 3;
  const int kcol = ((l & 7) ^ (l >> 3)) << 3;

  // V stage: thread reads V[row=vr][cols vc0..vc0+15], writes V^T swizzled
  const int vr = tid >> 2;
  const int vc0 = (tid & 3) << 4;

  f32x16 o0 = {}, o1 = {};
  float m_run = -1e30f, lsum = 0.f;
  bf16x8 v0, v1;
  const float L2E = 1.4426950408889634f;

  // ---- prologue: stage tile 0 into buffer 0
  {
    gload_lds16(Kp + (size_t)(w * 8 + krow) * 3072 + kcol, &lK[(w * 8) * 64]);
    gload_lds16(Kp + (size_t)(32 + w * 8 + krow) * 3072 + kcol, &lK[(32 + w * 8) * 64]);
    const unsigned short* vb = Vp + (size_t)vr * 3072 + vc0;
    v0 = *(const bf16x8*)vb;
    v1 = *(const bf16x8*)(vb + 8);
#pragma unroll
    for (int i2 = 0; i2 < 8; ++i2) {
      lVt[(vc0 + i2) * 72 + (vr ^ vc0)] = (unsigned short)v0[i2];
      lVt[(vc0 + 8 + i2) * 72 + (vr ^ vc0)] = (unsigned short)v1[i2];
    }
  }
  __syncthreads();

  for (int kt = 0; kt < 32; ++kt) {
    const int cur = kt & 1;
    const unsigned short* lKc = lK + cur * 4096;
    const unsigned short* lVc = lVt + cur * 4608;
    const bool stage = (kt < 31);

    // ---- issue next-tile staging early (hides HBM latency under compute)
    if (stage) {
      const unsigned short* kb = Kp + (size_t)(kt + 1) * 64 * 3072;
      unsigned short* lKn = lK + (cur ^ 1) * 4096;
      gload_lds16(kb + (size_t)(w * 8 + krow) * 3072 + kcol, lKn + (w * 8) * 64);
      gload_lds16(kb + (size_t)(32 + w * 8 + krow) * 3072 + kcol, lKn + (32 + w * 8) * 64);
      const unsigned short* vb = Vp + (size_t)(kt + 1) * 64 * 3072 + (size_t)vr * 3072 + vc0;
      v0 = *(const bf16x8*)vb;
      v1 = *(const bf16x8*)(vb + 8);
    }

    // ---- S^T = K * Q  (D[row=k][col=q]); sa[kt2] covers k = kt2*32 + crow(r,hi)
    f32x16 sa[2] = {{}, {}};
    __builtin_amdgcn_s_setprio(1);
#pragma unroll
    for (int kt2 = 0; kt2 < 2; ++kt2) {
#pragma unroll
      for (int s = 0; s < 4; ++s) {
        bf16x8 kf = *(const bf16x8*)&lKc[(kt2 * 32 + l31) * 64 + (((2 * s + hi) ^ l7) << 3)];
        sa[kt2] = __builtin_amdgcn_mfma_f32_32x32x16_bf16(kf, qf[s], sa[kt2], 0, 0, 0);
      }
    }
    __builtin_amdgcn_s_setprio(0);

    // ---- online softmax (defer-max, THR=8); row q = l&31 is lane-local
    float pmax = -1e30f;
#pragma unroll
    for (int r = 0; r < 16; r += 2) {
      float t0, t1;
      asm("v_max3_f32 %0, %1, %2, %3"
          : "=v"(t0) : "v"(sa[0][r]), "v"(sa[0][r + 1]), "v"(pmax));
      asm("v_max3_f32 %0, %1, %2, %3"
          : "=v"(t1) : "v"(sa[1][r]), "v"(sa[1][r + 1]), "v"(t0));
      pmax = t1;
    }
    pmax = fmaxf(pmax, __shfl_xor(pmax, 32));
    if (!__all(pmax <= m_run + 8.0f)) {
      const float mn = fmaxf(m_run, pmax);
      const float alpha = __expf(m_run - mn);
      m_run = mn;
      lsum *= alpha;
#pragma unroll
      for (int r = 0; r < 16; ++r) {
        const float ar = __shfl(alpha, (r & 3) + 8 * (r >> 2) + 4 * hi);
        o0[r] *= ar;
        o1[r] *= ar;
      }
    }
    // p = exp2(s*log2e - m2): fma + v_exp_f32 (no hidden mul)
    const float m2 = m_run * L2E;
    float rsa = 0.f, rsb = 0.f;
#pragma unroll
    for (int kt2 = 0; kt2 < 2; ++kt2) {
#pragma unroll
      for (int r = 0; r < 16; r += 2) {
        const float a0 = __builtin_fmaf(sa[kt2][r], L2E, -m2);
        const float a1 = __builtin_fmaf(sa[kt2][r + 1], L2E, -m2);
        float p0, p1;
        asm("v_exp_f32 %0, %1" : "=v"(p0) : "v"(a0));
        asm("v_exp_f32 %0, %1" : "=v"(p1) : "v"(a1));
        sa[kt2][r] = p0;
        sa[kt2][r + 1] = p1;
        rsa += p0;
        rsb += p1;
      }
    }
    float rs = rsa + rsb;
    rs += __shfl_xor(rs, 32);
    lsum += rs;

    // ---- P -> A-operand frags fully in-register: cvt_pk pairs + permlane32_swap
    __builtin_amdgcn_s_setprio(1);
#pragma unroll
    for (int ks = 0; ks < 4; ++ks) {
      const int kt2 = ks >> 1, k2 = (ks & 1) * 8;
      unsigned xa, xb, ya, yb;
      asm("v_cvt_pk_bf16_f32 %0, %1, %2"
          : "=v"(xa) : "v"(sa[kt2][k2 + 0]), "v"(sa[kt2][k2 + 1]));
      asm("v_cvt_pk_bf16_f32 %0, %1, %2"
          : "=v"(xb) : "v"(sa[kt2][k2 + 2]), "v"(sa[kt2][k2 + 3]));
      asm("v_cvt_pk_bf16_f32 %0, %1, %2"
          : "=v"(ya) : "v"(sa[kt2][k2 + 4]), "v"(sa[kt2][k2 + 5]));
      asm("v_cvt_pk_bf16_f32 %0, %1, %2"
          : "=v"(yb) : "v"(sa[kt2][k2 + 6]), "v"(sa[kt2][k2 + 7]));
      asm("v_permlane32_swap_b32 %0, %1" : "+v"(xa), "+v"(ya));
      asm("v_permlane32_swap_b32 %0, %1" : "+v"(xb), "+v"(yb));
      u32x4 pw;
      pw[0] = xa; pw[1] = xb; pw[2] = ya; pw[3] = yb;
      const bf16x8 pa = __builtin_bit_cast(bf16x8, pw);
#pragma unroll
      for (int nd = 0; nd < 2; ++nd) {
        const int vrow = nd * 32 + l31;
        const bf16x8 vf = *(const bf16x8*)
            &lVc[vrow * 72 + ((16 * ks + 8 * hi) ^ (vrow & 0x30))];
        if (nd == 0)
          o0 = __builtin_amdgcn_mfma_f32_32x32x16_bf16(pa, vf, o0, 0, 0, 0);
        else
          o1 = __builtin_amdgcn_mfma_f32_32x32x16_bf16(pa, vf, o1, 0, 0, 0);
      }
    }
    __builtin_amdgcn_s_setprio(0);

    // ---- deferred V^T write into next buffer
    if (stage) {
      unsigned short* lVn = lVt + (cur ^ 1) * 4608;
#pragma unroll
      for (int i2 = 0; i2 < 8; ++i2) {
        lVn[(vc0 + i2) * 72 + (vr ^ vc0)] = (unsigned short)v0[i2];
        lVn[(vc0 + 8 + i2) * 72 + (vr ^ vc0)] = (unsigned short)v1[i2];
      }
    }
    __syncthreads();
  }

  // ---- epilogue: O[q][d] / l[q]; lane holds rows crow(r,hi), cols d = nd*32 + l31
  const float linv = 1.0f / lsum;
#pragma unroll
  for (int r = 0; r < 16; ++r) {
    const int crow = (r & 3) + 8 * (r >> 2) + 4 * hi;
    const float lr = __shfl(linv, crow);
    unsigned short* orow =
        aout + (size_t)(b * 2048 + qbase + crow) * 1024 + h * 64 + l31;
    orow[0] = f2bf(o0[r] * lr);
    orow[32] = f2bf(o1[r] * lr);
  }
}

// ---------------------------------------------------------------- launch
extern "C" void kernel_launch(void* const* d_in, const int* in_sizes, int n_in,
                              void* d_out, int out_size, void* d_ws, size_t ws_size,
                              hipStream_t stream) {
  const float* x     = (const float*)d_in[0];
  const float* w_qkv = (const float*)d_in[1];
  const float* b_qkv = (const float*)d_in[2];
  const float* w_out = (const float*)d_in[3];
  const float* b_out = (const float*)d_in[4];
  float* out = (float*)d_out;

  char* ws = (char*)d_ws;
  unsigned short* x_bf    = (unsigned short*)(ws);             // 16 MB
  unsigned short* wqkv_bf = (unsigned short*)(ws + 16777216);  // 6 MB
  unsigned short* wout_bf = (unsigned short*)(ws + 23068672);  // 2 MB
  unsigned short* qkv     = (unsigned short*)(ws + 25165824);  // 48 MB
  unsigned short* aout    = (unsigned short*)(ws + 75497472);  // 16 MB
  float2* cs              = (float2*)(ws + 92274688);          // 512 KB

  cast_f32_bf16<<<2097152 / 256, 256, 0, stream>>>(x, x_bf, 2097152);
  cast_f32_bf16<<<786432 / 256, 256, 0, stream>>>(w_qkv, wqkv_bf, 786432);
  cast_f32_bf16<<<262144 / 256, 256, 0, stream>>>(w_out, wout_bf, 262144);
  rope_table<<<65536 / 256, 256, 0, stream>>>(cs);

  // qkv = x @ w_qkv^T + b_qkv   (M=8192, N=3072, K=1024), bf16 out
  gemm_bt<1><<<64 * 24, 256, 0, stream>>>(x_bf, wqkv_bf, b_qkv, qkv,
                                          8192, 3072, 1024);
  rope_apply<<<4194304 / 256, 256, 0, stream>>>(qkv, cs);
  attn_fwd<<<1024, 256, 0, stream>>>(qkv, aout);
  // out = attn @ w_out^T + b_out (M=8192, N=1024, K=1024), f32 out
  gemm_bt<0><<<64 * 8, 256, 0, stream>>>(aout, wout_bf, b_out, out,
                                         8192, 1024, 1024);
}